// Round 1
// baseline (142.554 us; speedup 1.0000x reference)
//
#include <hip/hip_runtime.h>

// Problem constants (from reference)
#define B_    4
#define A_    66000
#define N_    30
#define T_    5
#define NLT   5
#define CSUM  277            // sum(NUM_CLASSES)
#define CTOT  278            // 1 + CSUM
#define ROWS  31             // N+1
#define TBL   (B_ * ROWS * CSUM)   // 34348 floats
#define NPAIR (CTOT / 2)     // 139 float2 pairs per anchor

#define BLK        256
#define GRID_MAIN  2048
#define GRID_REG   512

// ---------------- helpers ----------------

// focal elem with y in {0,1}:
//   s = y ? -x : x;  elem = (y?0.25:0.75) * softplus(s) * sigmoid(s)^2
__device__ __forceinline__ float focal_elem(float x, float y) {
    float s  = (y > 0.5f) ? -x : x;
    float af = (y > 0.5f) ? 0.25f : 0.75f;
    float t  = __expf(-fabsf(s));          // exp(-|s|) in (0,1]
    float sp = fmaxf(s, 0.f) + __logf(1.f + t);   // softplus(s)
    float inv = 1.f / (1.f + t);
    float sig = (s >= 0.f) ? inv : t * inv;       // sigmoid(s)
    return af * sp * sig * sig;
}

__device__ __forceinline__ float sl1(float d) {
    float ad = fabsf(d);
    // BETA = 1/9: 0.5*ad*ad/BETA = 4.5*ad*ad ; ad - 0.5*BETA = ad - 1/18
    return (ad < (1.f / 9.f)) ? 4.5f * ad * ad : ad - (1.f / 18.f);
}

// block reduction; result valid in thread 0. Caller must __syncthreads()
// between consecutive uses of the same sdata.
__device__ __forceinline__ float block_reduce(float v, float* sdata) {
    #pragma unroll
    for (int off = 32; off > 0; off >>= 1) v += __shfl_down(v, off, 64);
    int lane = threadIdx.x & 63, wid = threadIdx.x >> 6;
    if (lane == 0) sdata[wid] = v;
    __syncthreads();
    int nw = blockDim.x >> 6;
    if (wid == 0) {
        v = (lane < nw) ? sdata[lane] : 0.f;
        #pragma unroll
        for (int off = 32; off > 0; off >>= 1) v += __shfl_down(v, off, 64);
    }
    return v;
}

// ---------------- kernels ----------------

// Build the concatenated (B, 31, 277) 0/1 table from gt_labels. One block.
__global__ void build_table(const int* __restrict__ gtl, float* __restrict__ ctable) {
    for (int i = threadIdx.x; i < TBL; i += blockDim.x) ctable[i] = 0.f;
    __syncthreads();
    int tid = threadIdx.x;
    if (tid < B_ * N_ * NLT) {
        int lt = tid % NLT;
        int bn = tid / NLT;
        int n  = bn % N_;
        int b  = bn / N_;
        const int nc_arr[NLT]  = {10, 23, 69, 163, 12};
        const int off_arr[NLT] = {0, 10, 33, 102, 265};
        int nc  = nc_arr[lt];
        int off = off_arr[lt];
        const int* g = gtl + (size_t)(((b * N_ + n) * NLT + lt)) * T_;
        float* row = ctable + (size_t)((b * ROWS + (n + 1)) * CSUM) + off;
        bool valid = true;
        #pragma unroll
        for (int t = 0; t < T_; ++t) {
            int v = g[t];
            valid = valid && (v >= 0);
            if (valid) {
                int c = (v < nc) ? v : (nc - 1);
                row[c] = 1.f;
            }
        }
    }
}

// Main classification focal-loss sum over all (anchor, class) elements.
__global__ __launch_bounds__(BLK) void cls_kernel(
    const float* __restrict__ conf, const int* __restrict__ lbin,
    const float* __restrict__ ctable, float* __restrict__ partials)
{
    const unsigned NE2 = (unsigned)(B_ * A_) * NPAIR;   // 36,696,000
    float acc = 0.f;
    unsigned stride = gridDim.x * blockDim.x;
    for (unsigned e = blockIdx.x * blockDim.x + threadIdx.x; e < NE2; e += stride) {
        unsigned anchor = e / NPAIR;               // magic-mul div by 139
        unsigned p = e - anchor * NPAIR;
        int lb = lbin[anchor];
        if (lb < 0) continue;                      // mask == 0
        float pos = (lb > 0) ? 1.f : 0.f;
        int dumy  = (lb > 0) ? lb : 0;
        unsigned b = anchor / A_;                  // magic-mul div by 66000
        const float* __restrict__ row = ctable + (size_t)((b * ROWS + dumy) * CSUM);
        float2 cv = *(const float2*)(conf + (size_t)anchor * CTOT + 2u * p);
        unsigned c0 = 2u * p;
        float y0 = (c0 == 0u) ? pos : row[c0 - 1];
        float y1 = row[c0];                        // class index c1-1 = 2p
        acc += focal_elem(cv.x, y0) + focal_elem(cv.y, y1);
    }
    __shared__ float sdata[BLK / 64];
    float r = block_reduce(acc, sdata);
    if (threadIdx.x == 0) partials[blockIdx.x] = r;
}

// Smooth-L1 regression numerator + positive count.
__global__ __launch_bounds__(BLK) void reg_kernel(
    const float* __restrict__ pred, const float* __restrict__ gt,
    const int* __restrict__ lbin,
    float* __restrict__ reg_part, float* __restrict__ pos_part)
{
    const unsigned NA = B_ * A_;
    float racc = 0.f, pacc = 0.f;
    unsigned stride = gridDim.x * blockDim.x;
    for (unsigned i = blockIdx.x * blockDim.x + threadIdx.x; i < NA; i += stride) {
        int lb = lbin[i];
        if (lb > 0) {
            pacc += 1.f;
            float4 pv = *(const float4*)(pred + (size_t)4 * i);
            float4 gv = *(const float4*)(gt + (size_t)4 * i);
            racc += sl1(pv.x - gv.x) + sl1(pv.y - gv.y) + sl1(pv.z - gv.z) + sl1(pv.w - gv.w);
        }
    }
    __shared__ float sdata[BLK / 64];
    float r = block_reduce(racc, sdata);
    __syncthreads();
    float p = block_reduce(pacc, sdata);
    if (threadIdx.x == 0) {
        reg_part[blockIdx.x] = r;
        pos_part[blockIdx.x] = p;
    }
}

// Deterministic final reduction + normalization.
__global__ void finalize_kernel(
    const float* __restrict__ cls_part, const float* __restrict__ reg_part,
    const float* __restrict__ pos_part, float* __restrict__ out)
{
    __shared__ float sdata[256 / 64];
    float c = 0.f, r = 0.f, pz = 0.f;
    for (int i = threadIdx.x; i < GRID_MAIN; i += blockDim.x) c += cls_part[i];
    for (int i = threadIdx.x; i < GRID_REG; i += blockDim.x) {
        r  += reg_part[i];
        pz += pos_part[i];
    }
    c = block_reduce(c, sdata);
    __syncthreads();
    r = block_reduce(r, sdata);
    __syncthreads();
    pz = block_reduce(pz, sdata);
    if (threadIdx.x == 0) {
        float np = fmaxf(1.f, pz);
        out[0] = r / (np * 4.f);   // regression_loss
        out[1] = c / np;           // cls_loss
    }
}

// ---------------- launch ----------------

extern "C" void kernel_launch(void* const* d_in, const int* in_sizes, int n_in,
                              void* d_out, int out_size, void* d_ws, size_t ws_size,
                              hipStream_t stream) {
    const float* conf = (const float*)d_in[0];
    const float* pred = (const float*)d_in[1];
    const float* gt   = (const float*)d_in[2];
    const int*   gtl  = (const int*)d_in[3];
    const int*   lbin = (const int*)d_in[4];
    float* out = (float*)d_out;

    float* ctable   = (float*)d_ws;
    float* cls_part = ctable + TBL;
    float* reg_part = cls_part + GRID_MAIN;
    float* pos_part = reg_part + GRID_REG;

    hipLaunchKernelGGL(build_table, dim3(1), dim3(1024), 0, stream, gtl, ctable);
    hipLaunchKernelGGL(cls_kernel, dim3(GRID_MAIN), dim3(BLK), 0, stream,
                       conf, lbin, ctable, cls_part);
    hipLaunchKernelGGL(reg_kernel, dim3(GRID_REG), dim3(BLK), 0, stream,
                       pred, gt, lbin, reg_part, pos_part);
    hipLaunchKernelGGL(finalize_kernel, dim3(1), dim3(256), 0, stream,
                       cls_part, reg_part, pos_part, out);
}

// Round 2
// 106.491 us; speedup vs baseline: 1.3387x; 1.3387x over previous
//
#include <hip/hip_runtime.h>

// Problem constants
#define B_    4
#define A_    66000
#define NA_   (B_ * A_)          // 264000 anchors
#define N_    30
#define T_    5
#define NLT   5
#define CSUM  277
#define CTOT  278                // 1 + 277 logits per anchor
#define ROWS  31                 // N+1 table rows per batch
#define NROWS (B_ * ROWS)        // 124
#define WPR   16                 // u32 words per bit-row (9 used, padded)
#define NBW   (NROWS * WPR)      // 1984 words = 7936 B
#define NE    (NA_ * CTOT)       // 73,392,000 elements
#define NQ    (NE / 4)           // 18,348,000 float4s (exact)

#define BLK       256
#define GRID_CLS  2048
#define GRID_REG  512

// ---------------- helpers ----------------

// focal elem, y in {0,1} as bit, coef = mask * (y ? 0.25 : 0.75):
//   s = y ? -x : x;  elem = coef * softplus(s) * sigmoid(s)^2
__device__ __forceinline__ float focal_c(float x, unsigned yb, float coef) {
    float s   = __int_as_float(__float_as_int(x) ^ (int)(yb << 31));
    float t   = __expf(-fabsf(s));                 // exp(-|s|) in (0,1]
    float sp  = fmaxf(s, 0.f) + __logf(1.f + t);   // softplus(s)
    float inv = __builtin_amdgcn_rcpf(1.f + t);
    float sig = (s >= 0.f) ? inv : t * inv;        // sigmoid(s)
    return coef * sp * sig * sig;
}

__device__ __forceinline__ float sl1(float d) {
    float ad = fabsf(d);
    return (ad < (1.f / 9.f)) ? 4.5f * ad * ad : ad - (1.f / 18.f);
}

// block reduction; result valid in thread 0.
__device__ __forceinline__ float block_reduce(float v, float* sdata) {
    #pragma unroll
    for (int off = 32; off > 0; off >>= 1) v += __shfl_down(v, off, 64);
    int lane = threadIdx.x & 63, wid = threadIdx.x >> 6;
    if (lane == 0) sdata[wid] = v;
    __syncthreads();
    int nw = blockDim.x >> 6;
    if (wid == 0) {
        v = (lane < nw) ? sdata[lane] : 0.f;
        #pragma unroll
        for (int off = 32; off > 0; off >>= 1) v += __shfl_down(v, off, 64);
    }
    return v;
}

// ---------------- kernels ----------------

// Bit-packed label table: 124 rows x 16 u32. Bit c of row (b*31+dumy) is the
// label y for logit column c (col 0 = pos bit, cols 1..277 = class table).
__global__ void build_bits(const int* __restrict__ gtl, unsigned* __restrict__ bits) {
    for (int i = threadIdx.x; i < NBW; i += blockDim.x) bits[i] = 0u;
    __syncthreads();
    int tid = threadIdx.x;
    if (tid < NROWS) {
        if ((tid % ROWS) > 0) atomicOr(&bits[tid * WPR], 1u);   // pos bit
    }
    if (tid < B_ * N_ * NLT) {
        int lt = tid % NLT;
        int bn = tid / NLT;
        int n  = bn % N_;
        int b  = bn / N_;
        const int nc_arr[NLT]  = {10, 23, 69, 163, 12};
        const int off_arr[NLT] = {0, 10, 33, 102, 265};
        int nc  = nc_arr[lt];
        int off = off_arr[lt] + 1;              // +1: col 0 is pos
        const int* g = gtl + (size_t)(((b * N_ + n) * NLT + lt)) * T_;
        int row = b * ROWS + (n + 1);
        bool valid = true;
        #pragma unroll
        for (int t = 0; t < T_; ++t) {
            int v = g[t];
            valid = valid && (v >= 0);
            if (valid) {
                int c = off + ((v < nc) ? v : (nc - 1));
                atomicOr(&bits[row * WPR + (c >> 5)], 1u << (c & 31));
            }
        }
    }
}

// Regression loss + pos count + per-anchor rowid (word offset into bits,
// -1 = masked-out anchor).
__global__ __launch_bounds__(BLK) void reg_rowid_kernel(
    const float* __restrict__ pred, const float* __restrict__ gt,
    const int* __restrict__ lbin, int* __restrict__ rowid,
    float* __restrict__ reg_part, float* __restrict__ pos_part)
{
    float racc = 0.f, pacc = 0.f;
    unsigned stride = gridDim.x * blockDim.x;
    for (unsigned i = blockIdx.x * blockDim.x + threadIdx.x; i < NA_; i += stride) {
        int lb = lbin[i];
        unsigned b = i / A_;
        rowid[i] = (lb < 0) ? -1 : (int)((b * ROWS + (unsigned)(lb > 0 ? lb : 0)) * WPR);
        if (lb > 0) {
            pacc += 1.f;
            float4 pv = *(const float4*)(pred + (size_t)4 * i);
            float4 gv = *(const float4*)(gt + (size_t)4 * i);
            racc += sl1(pv.x - gv.x) + sl1(pv.y - gv.y) + sl1(pv.z - gv.z) + sl1(pv.w - gv.w);
        }
    }
    __shared__ float sdata[BLK / 64];
    float r = block_reduce(racc, sdata);
    __syncthreads();
    float p = block_reduce(pacc, sdata);
    if (threadIdx.x == 0) {
        reg_part[blockIdx.x] = r;
        pos_part[blockIdx.x] = p;
    }
}

// Main classification focal-loss sum. Flat float4 grid-stride over conf.
__global__ __launch_bounds__(BLK) void cls_kernel(
    const float4* __restrict__ conf4, const int* __restrict__ rowid,
    const unsigned* __restrict__ bits, float* __restrict__ partials)
{
    __shared__ unsigned lbits[NBW];
    for (int i = threadIdx.x; i < NBW; i += BLK) lbits[i] = bits[i];
    __syncthreads();

    float acc = 0.f;
    unsigned stride = gridDim.x * blockDim.x;
    for (unsigned i = blockIdx.x * blockDim.x + threadIdx.x; i < NQ; i += stride) {
        float4 xv = conf4[i];                 // streaming traffic, independent
        unsigned i4 = i * 4u;
        unsigned a  = i4 / CTOT;              // magic-mul div
        unsigned c0 = i4 - a * CTOT;          // even, 0..276
        int rid = rowid[a];                   // L1-hit broadcast

        unsigned y0, y1, y2, y3;
        float m01, m23;
        if (c0 != 276u) {                     // all 4 elems in anchor a
            unsigned base = (rid >= 0) ? (unsigned)rid : 0u;
            unsigned w0 = lbits[base + (c0 >> 5)];
            unsigned w1 = lbits[base + ((c0 + 3u) >> 5)];
            unsigned sh = c0 & 31u;
            y0 = (w0 >> sh) & 1u;
            y1 = (w0 >> (sh + 1u)) & 1u;
            unsigned s2 = sh + 2u, s3 = sh + 3u;
            y2 = (((s2 > 31u) ? w1 : w0) >> (s2 & 31u)) & 1u;
            y3 = (((s3 > 31u) ? w1 : w0) >> (s3 & 31u)) & 1u;
            m01 = m23 = (rid >= 0) ? 1.f : 0.f;
        } else {                              // elems 276,277 of a; 0,1 of a+1
            int rid2 = rowid[a + 1u];
            unsigned wA = lbits[((rid  >= 0) ? (unsigned)rid  : 0u) + 8u];
            unsigned wB = lbits[ (rid2 >= 0) ? (unsigned)rid2 : 0u];
            y0 = (wA >> 20) & 1u;
            y1 = (wA >> 21) & 1u;
            y2 = wB & 1u;
            y3 = (wB >> 1) & 1u;
            m01 = (rid  >= 0) ? 1.f : 0.f;
            m23 = (rid2 >= 0) ? 1.f : 0.f;
        }
        float k0 = m01 * (y0 ? 0.25f : 0.75f);
        float k1 = m01 * (y1 ? 0.25f : 0.75f);
        float k2 = m23 * (y2 ? 0.25f : 0.75f);
        float k3 = m23 * (y3 ? 0.25f : 0.75f);
        acc += focal_c(xv.x, y0, k0) + focal_c(xv.y, y1, k1)
             + focal_c(xv.z, y2, k2) + focal_c(xv.w, y3, k3);
    }
    __shared__ float sdata[BLK / 64];
    float r = block_reduce(acc, sdata);
    if (threadIdx.x == 0) partials[blockIdx.x] = r;
}

// Deterministic final reduction + normalization.
__global__ void finalize_kernel(
    const float* __restrict__ cls_part, const float* __restrict__ reg_part,
    const float* __restrict__ pos_part, float* __restrict__ out)
{
    __shared__ float sdata[256 / 64];
    float c = 0.f, r = 0.f, pz = 0.f;
    for (int i = threadIdx.x; i < GRID_CLS; i += blockDim.x) c += cls_part[i];
    for (int i = threadIdx.x; i < GRID_REG; i += blockDim.x) {
        r  += reg_part[i];
        pz += pos_part[i];
    }
    c = block_reduce(c, sdata);
    __syncthreads();
    r = block_reduce(r, sdata);
    __syncthreads();
    pz = block_reduce(pz, sdata);
    if (threadIdx.x == 0) {
        float np = fmaxf(1.f, pz);
        out[0] = r / (np * 4.f);   // regression_loss
        out[1] = c / np;           // cls_loss
    }
}

// ---------------- launch ----------------

extern "C" void kernel_launch(void* const* d_in, const int* in_sizes, int n_in,
                              void* d_out, int out_size, void* d_ws, size_t ws_size,
                              hipStream_t stream) {
    const float* conf = (const float*)d_in[0];
    const float* pred = (const float*)d_in[1];
    const float* gt   = (const float*)d_in[2];
    const int*   gtl  = (const int*)d_in[3];
    const int*   lbin = (const int*)d_in[4];
    float* out = (float*)d_out;

    unsigned* bits  = (unsigned*)d_ws;
    int* rowid      = (int*)(bits + NBW);
    float* cls_part = (float*)(rowid + NA_);
    float* reg_part = cls_part + GRID_CLS;
    float* pos_part = reg_part + GRID_REG;

    hipLaunchKernelGGL(build_bits, dim3(1), dim3(1024), 0, stream, gtl, bits);
    hipLaunchKernelGGL(reg_rowid_kernel, dim3(GRID_REG), dim3(BLK), 0, stream,
                       pred, gt, lbin, rowid, reg_part, pos_part);
    hipLaunchKernelGGL(cls_kernel, dim3(GRID_CLS), dim3(BLK), 0, stream,
                       (const float4*)conf, rowid, bits, cls_part);
    hipLaunchKernelGGL(finalize_kernel, dim3(1), dim3(256), 0, stream,
                       cls_part, reg_part, pos_part, out);
}